// Round 4
// baseline (72.513 us; speedup 1.0000x reference)
//
#include <hip/hip_runtime.h>
#include <math.h>

// Problem: predict_pc 4x3x4096, gt_pc 4x3x4096 fp32; symmetric 1-NN chamfer mean.
// Inner-loop math: min d2 = p2+g2-2*p.g  <=>  max score = p.g - g2/2.
// Candidates staged in LDS as float4 (x, y, z, -g2/2) -> 3 fma + ~0.5 max per pair.
#define BATCH 4
#define NPTS 4096
#define THREADS 256
#define P 8                          // points per thread (VALU-bound; LDS reads are broadcasts)
#define SEGS 32                      // candidate segments
#define CSEG (NPTS / SEGS)           // 128 candidates per segment
#define PTGRPS (NPTS / (THREADS * P))        // 2 point-groups per (dir,batch)
#define PASS1_BLOCKS (2 * BATCH * PTGRPS * SEGS)  // 512 -> 2 waves/SIMD on 256 CUs
#define TOTAL_PTS (2 * BATCH * NPTS)         // 32768
#define PASS2_BLOCKS 128                     // 1 point per thread

#define EPS 1e-8f
#define BIG 1e30f

// ws layout: [0 .. SEGS*TOTAL_PTS) partial d2 mins (4MB); then acc (float), counter (int).
#define PMIN_FLOATS (SEGS * TOTAL_PTS)

__global__ __launch_bounds__(THREADS) void chamfer_pass1(
    const float* __restrict__ pred, const float* __restrict__ gt,
    float* __restrict__ pmin, float* __restrict__ acc, int* __restrict__ ctr)
{
    __shared__ float4 lc[CSEG];   // (x, y, z, -0.5*g2) per candidate

    // Re-init pass2's accumulator + arrival counter every call (ws is re-poisoned).
    // Stream order guarantees pass1 completes before pass2 starts.
    if (blockIdx.x == 0 && threadIdx.x == 0) { acc[0] = 0.0f; ctr[0] = 0; }

    const int bid   = blockIdx.x;
    const int seg   = bid & (SEGS - 1);
    const int ptgrp = (bid >> 5) & (PTGRPS - 1);
    const int batch = (bid >> 6) & (BATCH - 1);
    const int dir   = bid >> 8;

    const float* pts  = (dir == 0) ? pred : gt;
    const float* cand = (dir == 0) ? gt   : pred;

    // Stage this segment's 128 candidates (threads 0..127), computing -g2/2.
    if (threadIdx.x < CSEG) {
        const float* cb = cand + (size_t)batch * 3 * NPTS + seg * CSEG;
        const float x = cb[threadIdx.x];
        const float y = cb[NPTS + threadIdx.x];
        const float z = cb[2 * NPTS + threadIdx.x];
        const float s = -0.5f * fmaf(x, x, fmaf(y, y, z * z));
        lc[threadIdx.x] = make_float4(x, y, z, s);
    }
    __syncthreads();

    // This thread's 8 points (coalesced, stride-256 within the 2048-pt group).
    const float* pb = pts + (size_t)batch * 3 * NPTS;
    const int pbase = ptgrp * (THREADS * P) + threadIdx.x;
    float px[P], py[P], pz[P], smax[P];
    #pragma unroll
    for (int k = 0; k < P; ++k) {
        const int i = pbase + k * THREADS;
        px[k] = pb[i];
        py[k] = pb[NPTS + i];
        pz[k] = pb[2 * NPTS + i];
        smax[k] = -BIG;
    }

    // 32 groups of 4 candidates. LDS reads are wave-uniform (broadcast, ~free);
    // VALU: 4*P*(3 fma) + P*2 max3 per group.
    #pragma unroll 2
    for (int g = 0; g < CSEG / 4; ++g) {
        const float4 c0 = lc[4 * g + 0];
        const float4 c1 = lc[4 * g + 1];
        const float4 c2 = lc[4 * g + 2];
        const float4 c3 = lc[4 * g + 3];
        #pragma unroll
        for (int k = 0; k < P; ++k) {
            float t0 = fmaf(px[k], c0.x, fmaf(py[k], c0.y, fmaf(pz[k], c0.z, c0.w)));
            float t1 = fmaf(px[k], c1.x, fmaf(py[k], c1.y, fmaf(pz[k], c1.z, c1.w)));
            float t2 = fmaf(px[k], c2.x, fmaf(py[k], c2.y, fmaf(pz[k], c2.z, c2.w)));
            float t3 = fmaf(px[k], c3.x, fmaf(py[k], c3.y, fmaf(pz[k], c3.z, c3.w)));
            smax[k] = fmaxf(smax[k], fmaxf(fmaxf(t0, t1), fmaxf(t2, t3)));
        }
    }

    // Convert back to d2 and store: pmin[seg][global_point], coalesced per k.
    const int gp = dir * (BATCH * NPTS) + batch * NPTS + pbase;
    #pragma unroll
    for (int k = 0; k < P; ++k) {
        const float p2 = fmaf(px[k], px[k], fmaf(py[k], py[k], pz[k] * pz[k]));
        pmin[(size_t)seg * TOTAL_PTS + gp + k * THREADS] = fmaf(-2.0f, smax[k], p2);
    }
}

// Pass 2 (fused finalize): per point min over 32 segment d2s, clamp, sqrt(+eps),
// block-sum, atomic-accumulate; last-arriving block writes the scalar mean.
__global__ __launch_bounds__(THREADS) void chamfer_pass2(
    const float* __restrict__ pmin, float* __restrict__ acc, int* __restrict__ ctr,
    float* __restrict__ out)
{
    const int p = blockIdx.x * THREADS + threadIdx.x;   // one point per thread
    float v = BIG;
    #pragma unroll
    for (int s = 0; s < SEGS; ++s)
        v = fminf(v, pmin[(size_t)s * TOTAL_PTS + p]);
    float r = sqrtf(fmaxf(v, 0.0f) + EPS);

    #pragma unroll
    for (int off = 32; off; off >>= 1) r += __shfl_down(r, off, 64);
    __shared__ float wsum[THREADS / 64];
    if ((threadIdx.x & 63) == 0) wsum[threadIdx.x >> 6] = r;
    __syncthreads();

    if (threadIdx.x == 0) {
        const float bs = (wsum[0] + wsum[1]) + (wsum[2] + wsum[3]);
        atomicAdd(acc, bs);                 // device-scope by default
        __threadfence();
        const int t = atomicAdd(ctr, 1);
        if (t == PASS2_BLOCKS - 1) {
            __threadfence();
            const float total = atomicAdd(acc, 0.0f);   // atomic read of final sum
            out[0] = total * (1.0f / (float)(BATCH * NPTS));
        }
    }
}

extern "C" void kernel_launch(void* const* d_in, const int* in_sizes, int n_in,
                              void* d_out, int out_size, void* d_ws, size_t ws_size,
                              hipStream_t stream) {
    const float* pred = (const float*)d_in[0];
    const float* gt   = (const float*)d_in[1];
    float* out  = (float*)d_out;
    float* pmin = (float*)d_ws;                 // 4MB partial d2 mins (all slots written)
    float* acc  = pmin + PMIN_FLOATS;           // scalar accumulator
    int*   ctr  = (int*)(acc + 1);              // arrival counter

    chamfer_pass1<<<PASS1_BLOCKS, THREADS, 0, stream>>>(pred, gt, pmin, acc, ctr);
    chamfer_pass2<<<PASS2_BLOCKS, THREADS, 0, stream>>>(pmin, acc, ctr, out);
}